// Round 1
// baseline (423.639 us; speedup 1.0000x reference)
//
#include <hip/hip_runtime.h>

#define DIM 192
#define NTOK 64
#define NHEAD 6
#define HDIM 32
#define SCALE 0.17677669529663687f

typedef __attribute__((ext_vector_type(8))) short bf16x8;
typedef __attribute__((ext_vector_type(4))) float f32x4;

__device__ __forceinline__ ushort f2bf(float f) {
    union { float f; unsigned u; } x; x.f = f;
    unsigned r = x.u + 0x7FFFu + ((x.u >> 16) & 1u);
    return (ushort)(r >> 16);
}
__device__ __forceinline__ float bf2f(ushort h) {
    union { unsigned u; float f; } x; x.u = ((unsigned)h) << 16;
    return x.f;
}

__device__ __forceinline__ f32x4 MF(bf16x8 a, bf16x8 b, f32x4 c) {
    return __builtin_amdgcn_mfma_f32_16x16x32_bf16(a, b, c, 0, 0, 0);
}

// A/B fragment load for 16x16x32 bf16 mfma from a row-major bf16 matrix.
// "row" index -> lane&15 ; k -> (lane>>4)*8 + j (8 contiguous bf16 = 16B load)
__device__ __forceinline__ bf16x8 frag(const ushort* base, int stride, int r0, int k0) {
    const int l = threadIdx.x & 63;
    return *(const bf16x8*)(base + (r0 + (l & 15)) * stride + (k0 + ((l >> 4) << 3)));
}

__global__ void prep_weights(const float* __restrict__ qw, const float* __restrict__ kvw,
                             const float* __restrict__ pw, ushort* __restrict__ wbf) {
    int i = blockIdx.x * 256 + threadIdx.x;
    if (i < 36864) wbf[i] = f2bf(qw[i]);
    else if (i < 110592) wbf[i] = f2bf(kvw[i - 36864]);
    else if (i < 147456) wbf[i] = f2bf(pw[i - 110592]);
}

__global__ __launch_bounds__(512, 2) void fused_win_attn(
    const float* __restrict__ x1, const float* __restrict__ x2,
    const float* __restrict__ mask, const float* __restrict__ qb,
    const float* __restrict__ kvb, const float* __restrict__ rpb,
    const float* __restrict__ gammap, const float* __restrict__ pb,
    const ushort* __restrict__ qwbf, const ushort* __restrict__ kvwbf,
    const ushort* __restrict__ pwbf, float* __restrict__ out)
{
    // strides (elems) all multiples of 8 -> 16B-aligned frag loads, <=2-way bank conflict
    __shared__ __align__(16) ushort sX[64 * 200];     // x2 | x1 | finalX      (25600 B)
    __shared__ __align__(16) ushort sQP[6 * 64 * 40]; // Q per head, then P    (30720 B)
    __shared__ __align__(16) ushort sK[6 * 64 * 40];  // K [m][d]; later E/att (30720 B)
    __shared__ __align__(16) ushort sVY[6 * 32 * 72]; // V^T [d][m], then Y    (27648 B)
    __shared__ __align__(16) ushort sR[64 * 192];     // residual q*s + x1     (24576 B)
    __shared__ __align__(16) ushort sRPB[1352];       // rel-pos bias bf16     ( 2704 B)

    const int tid  = threadIdx.x;
    const int wave = tid >> 6;
    const int lane = tid & 63;
    const int g    = lane >> 4;   // lane group 0..3
    const int mcol = lane & 15;
    const int b    = blockIdx.x;
    const float gamma = gammap[0];

    // P0: rpb -> LDS (bf16)
    for (int i = tid; i < 1350; i += 512) sRPB[i] = f2bf(rpb[i]);
    // P1: x2 -> sX (bf16)
    {
        const float4* src = (const float4*)(x2 + (size_t)b * (NTOK * DIM));
        for (int i = tid; i < 3072; i += 512) {
            float4 v = src[i];
            int e = i << 2; int n = e / DIM; int c = e - n * DIM;
            ushort4 w; w.x = f2bf(v.x); w.y = f2bf(v.y); w.z = f2bf(v.z); w.w = f2bf(v.w);
            *(ushort4*)(&sX[n * 200 + c]) = w;
        }
    }
    __syncthreads();

    // P2: kv = x2 @ kvw^T + kvb ; K -> sK[h][m][d], V -> sVY[h][d][m] (transposed)
    {
        const int rt = wave & 3;
        bf16x8 af[6];
#pragma unroll
        for (int ks = 0; ks < 6; ++ks) af[ks] = frag(sX, 200, rt * 16, ks * 32);
        for (int ct = (wave >> 2); ct < 24; ct += 2) {
            f32x4 acc = {0.f, 0.f, 0.f, 0.f};
#pragma unroll
            for (int ks = 0; ks < 6; ++ks)
                acc = MF(af[ks], frag(kvwbf, DIM, ct * 16, ks * 32), acc);
            int co = ct * 16 + mcol;
            float bv = kvb[co];
            int r0 = rt * 16 + (g << 2);
            if (co < DIM) {                         // K part
                int h = co >> 5, d = co & 31;
                ushort* dst = sK + h * (64 * 40);
#pragma unroll
                for (int j = 0; j < 4; ++j) dst[(r0 + j) * 40 + d] = f2bf(acc[j] + bv);
            } else {                                // V part, transposed store
                int cv = co - DIM; int h = cv >> 5, d = cv & 31;
                ushort4 w4;
#pragma unroll
                for (int j = 0; j < 4; ++j) ((ushort*)&w4)[j] = f2bf(acc[j] + bv);
                *(ushort4*)(&sVY[h * (32 * 72) + d * 72 + r0]) = w4;
            }
        }
    }
    __syncthreads();

    // P3: x1 -> sX (bf16)
    {
        const float4* src = (const float4*)(x1 + (size_t)b * (NTOK * DIM));
        for (int i = tid; i < 3072; i += 512) {
            float4 v = src[i];
            int e = i << 2; int n = e / DIM; int c = e - n * DIM;
            ushort4 w; w.x = f2bf(v.x); w.y = f2bf(v.y); w.z = f2bf(v.z); w.w = f2bf(v.w);
            *(ushort4*)(&sX[n * 200 + c]) = w;
        }
    }
    __syncthreads();

    // P4: q = (x1 @ qw^T + qb) * SCALE -> sQP[h][n][d]; residual r = q + x1 -> sR
    {
        const int rt = wave & 3;
        bf16x8 af[6];
#pragma unroll
        for (int ks = 0; ks < 6; ++ks) af[ks] = frag(sX, 200, rt * 16, ks * 32);
        for (int ct = (wave >> 2); ct < 12; ct += 2) {
            f32x4 acc = {0.f, 0.f, 0.f, 0.f};
#pragma unroll
            for (int ks = 0; ks < 6; ++ks)
                acc = MF(af[ks], frag(qwbf, DIM, ct * 16, ks * 32), acc);
            int co = ct * 16 + mcol;
            float bv = qb[co];
            int h = co >> 5, d = co & 31;
            int r0 = rt * 16 + (g << 2);
            ushort* dq = sQP + h * (64 * 40);
#pragma unroll
            for (int j = 0; j < 4; ++j) {
                float qv = (acc[j] + bv) * SCALE;
                dq[(r0 + j) * 40 + d] = f2bf(qv);
                float xv = bf2f(sX[(r0 + j) * 200 + co]);
                sR[(r0 + j) * DIM + co] = f2bf(qv + xv);
            }
        }
    }
    __syncthreads();

    // P5: per-head attention; wave h owns head h
    if (wave < NHEAD) {
        const int h = wave;
        const ushort* Qh = sQP + h * (64 * 40);
        const ushort* Kh = sK  + h * (64 * 40);
        f32x4 acc[4][4];
        bf16x8 qa[4], kb[4];
#pragma unroll
        for (int rt = 0; rt < 4; ++rt) qa[rt] = frag(Qh, 40, rt * 16, 0);
#pragma unroll
        for (int ct = 0; ct < 4; ++ct) kb[ct] = frag(Kh, 40, ct * 16, 0);
        f32x4 zero4 = {0.f, 0.f, 0.f, 0.f};
#pragma unroll
        for (int rt = 0; rt < 4; ++rt)
#pragma unroll
            for (int ct = 0; ct < 4; ++ct)
                acc[rt][ct] = MF(qa[rt], kb[ct], zero4);
        // relative-position bias (closed-form index) + mask
        const float* mp = mask + (size_t)(b & 63) * 4096;
#pragma unroll
        for (int rt = 0; rt < 4; ++rt)
#pragma unroll
            for (int ct = 0; ct < 4; ++ct)
#pragma unroll
                for (int j = 0; j < 4; ++j) {
                    int n = rt * 16 + (g << 2) + j;
                    int m = ct * 16 + mcol;
                    int ridx = ((n >> 3) - (m >> 3) + 7) * 15 + ((n & 7) - (m & 7) + 7);
                    acc[rt][ct][j] += bf2f(sRPB[ridx * 6 + h]) + mp[n * 64 + m];
                }
        // row softmax (cols live in 16-lane groups x 4 ct-tiles)
        float sm[4][4];   // stores reciprocal of row sum
#pragma unroll
        for (int rt = 0; rt < 4; ++rt)
#pragma unroll
            for (int j = 0; j < 4; ++j) {
                float v = fmaxf(fmaxf(acc[rt][0][j], acc[rt][1][j]),
                                fmaxf(acc[rt][2][j], acc[rt][3][j]));
                v = fmaxf(v, __shfl_xor(v, 1, 64));
                v = fmaxf(v, __shfl_xor(v, 2, 64));
                v = fmaxf(v, __shfl_xor(v, 4, 64));
                v = fmaxf(v, __shfl_xor(v, 8, 64));
                float s = 0.f;
#pragma unroll
                for (int ct = 0; ct < 4; ++ct) {
                    float p = __expf(acc[rt][ct][j] - v);
                    acc[rt][ct][j] = p; s += p;
                }
                s += __shfl_xor(s, 1, 64);
                s += __shfl_xor(s, 2, 64);
                s += __shfl_xor(s, 4, 64);
                s += __shfl_xor(s, 8, 64);
                sm[rt][j] = 1.0f / s;
            }
        // PV: stage P (bf16, unnormalized) into dead Q buffer, 2 chunks of K=32
        ushort* Ph = sQP + h * (64 * 40);
        const ushort* Vh = sVY + h * (32 * 72);
        f32x4 accy[4][2];
#pragma unroll
        for (int rt = 0; rt < 4; ++rt)
#pragma unroll
            for (int ctd = 0; ctd < 2; ++ctd) accy[rt][ctd] = zero4;
#pragma unroll
        for (int c = 0; c < 2; ++c) {
#pragma unroll
            for (int rt = 0; rt < 4; ++rt)
#pragma unroll
                for (int dct = 0; dct < 2; ++dct)
#pragma unroll
                    for (int j = 0; j < 4; ++j) {
                        int row = rt * 16 + (g << 2) + j;
                        Ph[row * 40 + dct * 16 + mcol] = f2bf(acc[rt][2 * c + dct][j]);
                    }
            asm volatile("s_waitcnt lgkmcnt(0)" ::: "memory");
#pragma unroll
            for (int rt = 0; rt < 4; ++rt) {
                bf16x8 pa = frag(Ph, 40, rt * 16, 0);
#pragma unroll
                for (int ctd = 0; ctd < 2; ++ctd) {
                    bf16x8 vb = frag(Vh, 72, ctd * 16, c * 32);
                    accy[rt][ctd] = MF(pa, vb, accy[rt][ctd]);
                }
            }
            asm volatile("s_waitcnt lgkmcnt(0)" ::: "memory");
        }
        // normalize and write Y (= flat rows for this head) over dead V region
        ushort* Yh = sVY + h * (32 * 72);
#pragma unroll
        for (int rt = 0; rt < 4; ++rt)
#pragma unroll
            for (int ctd = 0; ctd < 2; ++ctd) {
                int d = ctd * 16 + mcol;
                int n0 = rt * 16 + (g << 2);
                ushort4 w4;
#pragma unroll
                for (int j = 0; j < 4; ++j)
                    ((ushort*)&w4)[j] = f2bf(accy[rt][ctd][j] * sm[rt][j]);
                *(ushort4*)(&Yh[d * 72 + n0]) = w4;
            }
    }
    __syncthreads();

    // P6: LAM energy = flat @ flat^T  [32x32], K=384 (waves 0..3); sE aliases dead sK
    float*  sE   = (float*)sK;        // [32][33] f32 = 4224 B
    ushort* sAtt = sK + 2112;         // [32][40] bf16, 16B-aligned
    if (wave < 4) {
        int rt = wave >> 1, ct = wave & 1;
        f32x4 acc = {0.f, 0.f, 0.f, 0.f};
        for (int h = 0; h < 6; ++h) {
            const ushort* Yh = sVY + h * (32 * 72);
#pragma unroll
            for (int kk = 0; kk < 2; ++kk) {
                bf16x8 a  = frag(Yh, 72, rt * 16, kk * 32);
                bf16x8 bb = frag(Yh, 72, ct * 16, kk * 32);
                acc = MF(a, bb, acc);
            }
        }
#pragma unroll
        for (int j = 0; j < 4; ++j) {
            int i = rt * 16 + (g << 2) + j;
            sE[i * 33 + ct * 16 + mcol] = acc[j];
        }
    }
    __syncthreads();

    // P7: softmax rows of energy -> att bf16
    if (tid < 32) {
        int r = tid;
        float mx = -1e30f;
#pragma unroll
        for (int j = 0; j < 32; ++j) mx = fmaxf(mx, sE[r * 33 + j]);
        float s = 0.f;
        float ev[32];
#pragma unroll
        for (int j = 0; j < 32; ++j) { ev[j] = __expf(sE[r * 33 + j] - mx); s += ev[j]; }
        float rs = 1.0f / s;
#pragma unroll
        for (int j = 0; j < 32; ++j) sAtt[r * 40 + j] = f2bf(ev[j] * rs);
    }
    __syncthreads();

    // P8: outm = att @ flat ; finalX[n][h*32+d] = gamma*outm + flat + r  -> sX (bf16)
    for (int t = wave; t < 48; t += 8) {
        int rt = t & 1, ct = t >> 1;          // ct 0..23 over k' = h*64+n
        int col = ct * 16 + mcol;
        int hh = col >> 6, nn = col & 63;
        const ushort* Yh = sVY + hh * (32 * 72);
        bf16x8 aa = frag(sAtt, 40, rt * 16, 0);
        bf16x8 bb;
#pragma unroll
        for (int jj = 0; jj < 8; ++jj) bb[jj] = (short)Yh[((g << 3) + jj) * 72 + nn];
        f32x4 zero4 = {0.f, 0.f, 0.f, 0.f};
        f32x4 acc = MF(aa, bb, zero4);
        ushort4 w4;
#pragma unroll
        for (int j = 0; j < 4; ++j) {
            int d = rt * 16 + (g << 2) + j;
            float flatv = bf2f(Yh[d * 72 + nn]);
            float val = gamma * acc[j] + flatv;
            float rv = bf2f(sR[nn * DIM + hh * 32 + d]);
            ((ushort*)&w4)[j] = f2bf(val + rv);
        }
        *(ushort4*)(&sX[nn * 200 + hh * 32 + rt * 16 + (g << 2)]) = w4;
    }
    __syncthreads();

    // P9: out = finalX @ pw^T + pb  (f32 global store)
    {
        float* outp = out + (size_t)b * (NTOK * DIM);
        const int rt = wave & 3;
        bf16x8 af[6];
#pragma unroll
        for (int ks = 0; ks < 6; ++ks) af[ks] = frag(sX, 200, rt * 16, ks * 32);
        for (int ct = (wave >> 2); ct < 12; ct += 2) {
            f32x4 acc = {0.f, 0.f, 0.f, 0.f};
#pragma unroll
            for (int ks = 0; ks < 6; ++ks)
                acc = MF(af[ks], frag(pwbf, DIM, ct * 16, ks * 32), acc);
            int co = ct * 16 + mcol;
            float pbv = pb[co];
#pragma unroll
            for (int j = 0; j < 4; ++j) {
                int n = rt * 16 + (g << 2) + j;
                outp[n * DIM + co] = acc[j] + pbv;
            }
        }
    }
}

extern "C" void kernel_launch(void* const* d_in, const int* in_sizes, int n_in,
                              void* d_out, int out_size, void* d_ws, size_t ws_size,
                              hipStream_t stream) {
    const float* x1    = (const float*)d_in[0];
    const float* x2    = (const float*)d_in[1];
    const float* mask  = (const float*)d_in[2];
    const float* qw    = (const float*)d_in[3];
    const float* qb    = (const float*)d_in[4];
    const float* kvw   = (const float*)d_in[5];
    const float* kvb   = (const float*)d_in[6];
    const float* rpb   = (const float*)d_in[7];
    const float* gamma = (const float*)d_in[8];
    const float* pw    = (const float*)d_in[9];
    const float* pb    = (const float*)d_in[10];
    ushort* wbf = (ushort*)d_ws;   // qw_bf | kvw_bf | pw_bf  (294,912 B total)

    prep_weights<<<576, 256, 0, stream>>>(qw, kvw, pw, wbf);
    fused_win_attn<<<2048, 512, 0, stream>>>(x1, x2, mask, qb, kvb, rpb, gamma, pb,
                                             wbf, wbf + 36864, wbf + 110592,
                                             (float*)d_out);
}

// Round 2
// 332.885 us; speedup vs baseline: 1.2726x; 1.2726x over previous
//
#include <hip/hip_runtime.h>

#define DIM 192
#define NTOK 64
#define NHEAD 6
#define HDIM 32
#define SCALE 0.17677669529663687f

typedef __attribute__((ext_vector_type(8))) short bf16x8;
typedef __attribute__((ext_vector_type(4))) float f32x4;

__device__ __forceinline__ ushort f2bf(float f) {
    union { float f; unsigned u; } x; x.f = f;
    unsigned r = x.u + 0x7FFFu + ((x.u >> 16) & 1u);
    return (ushort)(r >> 16);
}
__device__ __forceinline__ float bf2f(ushort h) {
    union { unsigned u; float f; } x; x.u = ((unsigned)h) << 16;
    return x.f;
}

__device__ __forceinline__ f32x4 MF(bf16x8 a, bf16x8 b, f32x4 c) {
    return __builtin_amdgcn_mfma_f32_16x16x32_bf16(a, b, c, 0, 0, 0);
}

// A/B fragment load for 16x16x32 bf16 mfma from a row-major bf16 matrix.
// row -> lane&15 ; k -> (lane>>4)*8 + j (8 contiguous bf16 = 16B load)
__device__ __forceinline__ bf16x8 frag(const ushort* base, int stride, int r0, int k0) {
    const int l = threadIdx.x & 63;
    return *(const bf16x8*)(base + (r0 + (l & 15)) * stride + (k0 + ((l >> 4) << 3)));
}

__global__ void prep_weights(const float* __restrict__ qw, const float* __restrict__ kvw,
                             const float* __restrict__ pw, ushort* __restrict__ wbf) {
    int i = blockIdx.x * 256 + threadIdx.x;
    if (i < 36864) wbf[i] = f2bf(qw[i]);
    else if (i < 110592) wbf[i] = f2bf(kvw[i - 36864]);
    else if (i < 147456) wbf[i] = f2bf(pw[i - 110592]);
}

// cmb[w][h][m][n] = rpb_bias(h,n,m) + mask[w][n][m]   (bf16, 3 MB)
__global__ void prep_cmb(const float* __restrict__ rpb, const float* __restrict__ mask,
                         ushort* __restrict__ cmb) {
    int t = blockIdx.x * 256 + threadIdx.x;   // 393216 threads, 4 elems each
    int e = t << 2;
    int n0 = e & 63;
    int m  = (e >> 6) & 63;
    int hw = e >> 12;
    int h = hw % 6, w = hw / 6;
#pragma unroll
    for (int j = 0; j < 4; ++j) {
        int n = n0 + j;
        int ridx = ((n >> 3) - (m >> 3) + 7) * 15 + ((n & 7) - (m & 7) + 7);
        float v = rpb[ridx * 6 + h] + mask[(w * 64 + n) * 64 + m];
        cmb[e + j] = f2bf(v);
    }
}

// ---------------- Kernel A: projections -> fragment-linear Q/K/V ----------------
__global__ __launch_bounds__(256, 3) void proj_qkv(
    const float* __restrict__ x1, const float* __restrict__ x2,
    const float* __restrict__ qb, const float* __restrict__ kvb,
    const ushort* __restrict__ qwbf, const ushort* __restrict__ kvwbf,
    ushort* __restrict__ Qf, ushort* __restrict__ Kf, ushort* __restrict__ Vf)
{
    __shared__ __align__(16) ushort sXA[64 * 200];   // 25600 B
    __shared__ __align__(16) ushort stg[4 * 2560];   // 20480 B (per-wave staging)
    const int tid = threadIdx.x, wave = tid >> 6, lane = tid & 63;
    const int g = lane >> 4, mcol = lane & 15;
    const int b = blockIdx.x;
    ushort* st = stg + wave * 2560;

    // stage x2 -> LDS bf16
    {
        const float4* src = (const float4*)(x2 + (size_t)b * 12288);
        for (int i = tid; i < 3072; i += 256) {
            float4 v = src[i];
            int e = i << 2; int n = e / DIM; int c = e - n * DIM;
            ushort4 w;
            ((ushort*)&w)[0] = f2bf(v.x); ((ushort*)&w)[1] = f2bf(v.y);
            ((ushort*)&w)[2] = f2bf(v.z); ((ushort*)&w)[3] = f2bf(v.w);
            *(ushort4*)(&sXA[n * 200 + c]) = w;
        }
    }
    __syncthreads();

    // 12 K/V head-tiles, per-wave independent
    for (int t = wave; t < 12; t += 4) {
        const int isV = (t >= 6) ? 1 : 0;
        const int h = isV ? (t - 6) : t;
        bf16x8 wf[2][6];
#pragma unroll
        for (int c2 = 0; c2 < 2; ++c2) {
            int ctg = (isV ? (12 + 2 * h) : (2 * h)) + c2;
#pragma unroll
            for (int ks = 0; ks < 6; ++ks)
                wf[c2][ks] = frag(kvwbf, DIM, ctg * 16, ks * 32);
        }
        f32x4 acc[4][2];
#pragma unroll
        for (int rt = 0; rt < 4; ++rt)
#pragma unroll
            for (int c2 = 0; c2 < 2; ++c2) acc[rt][c2] = (f32x4){0.f, 0.f, 0.f, 0.f};
#pragma unroll
        for (int rt = 0; rt < 4; ++rt) {
            bf16x8 af[6];
#pragma unroll
            for (int ks = 0; ks < 6; ++ks) af[ks] = frag(sXA, 200, rt * 16, ks * 32);
#pragma unroll
            for (int c2 = 0; c2 < 2; ++c2)
#pragma unroll
                for (int ks = 0; ks < 6; ++ks)
                    acc[rt][c2] = MF(af[ks], wf[c2][ks], acc[rt][c2]);
        }
        if (!isV) {                 // K: stage [m][d] stride 40, frags over m
#pragma unroll
            for (int c2 = 0; c2 < 2; ++c2) {
                float bv = kvb[h * 32 + c2 * 16 + mcol];
#pragma unroll
                for (int rt = 0; rt < 4; ++rt)
#pragma unroll
                    for (int j = 0; j < 4; ++j)
                        st[(rt * 16 + (g << 2) + j) * 40 + c2 * 16 + mcol] = f2bf(acc[rt][c2][j] + bv);
            }
            asm volatile("s_waitcnt lgkmcnt(0)" ::: "memory");
#pragma unroll
            for (int ct = 0; ct < 4; ++ct) {
                bf16x8 fr = frag(st, 40, ct * 16, 0);
                *(bf16x8*)(Kf + ((size_t)(b * 6 + h) * 4 + ct) * 512 + lane * 8) = fr;
            }
            asm volatile("s_waitcnt lgkmcnt(0)" ::: "memory");
        } else {                    // V: stage transposed [d][m] stride 72
#pragma unroll
            for (int c2 = 0; c2 < 2; ++c2) {
                float bv = kvb[192 + h * 32 + c2 * 16 + mcol];
#pragma unroll
                for (int rt = 0; rt < 4; ++rt) {
                    ushort4 w4;
#pragma unroll
                    for (int j = 0; j < 4; ++j) ((ushort*)&w4)[j] = f2bf(acc[rt][c2][j] + bv);
                    *(ushort4*)(&st[(c2 * 16 + mcol) * 72 + rt * 16 + (g << 2)]) = w4;
                }
            }
            asm volatile("s_waitcnt lgkmcnt(0)" ::: "memory");
#pragma unroll
            for (int c = 0; c < 2; ++c)
#pragma unroll
                for (int ctd = 0; ctd < 2; ++ctd) {
                    bf16x8 fr = frag(st, 72, ctd * 16, c * 32);
                    *(bf16x8*)(Vf + (((size_t)(b * 6 + h) * 2 + c) * 2 + ctd) * 512 + lane * 8) = fr;
                }
            asm volatile("s_waitcnt lgkmcnt(0)" ::: "memory");
        }
    }
    __syncthreads();

    // stage x1 -> LDS bf16
    {
        const float4* src = (const float4*)(x1 + (size_t)b * 12288);
        for (int i = tid; i < 3072; i += 256) {
            float4 v = src[i];
            int e = i << 2; int n = e / DIM; int c = e - n * DIM;
            ushort4 w;
            ((ushort*)&w)[0] = f2bf(v.x); ((ushort*)&w)[1] = f2bf(v.y);
            ((ushort*)&w)[2] = f2bf(v.z); ((ushort*)&w)[3] = f2bf(v.w);
            *(ushort4*)(&sXA[n * 200 + c]) = w;
        }
    }
    __syncthreads();

    // 6 Q head-tiles (pre-scaled)
    for (int t = wave; t < 6; t += 4) {
        const int h = t;
        bf16x8 wf[2][6];
#pragma unroll
        for (int c2 = 0; c2 < 2; ++c2)
#pragma unroll
            for (int ks = 0; ks < 6; ++ks)
                wf[c2][ks] = frag(qwbf, DIM, (2 * h + c2) * 16, ks * 32);
        f32x4 acc[4][2];
#pragma unroll
        for (int rt = 0; rt < 4; ++rt)
#pragma unroll
            for (int c2 = 0; c2 < 2; ++c2) acc[rt][c2] = (f32x4){0.f, 0.f, 0.f, 0.f};
#pragma unroll
        for (int rt = 0; rt < 4; ++rt) {
            bf16x8 af[6];
#pragma unroll
            for (int ks = 0; ks < 6; ++ks) af[ks] = frag(sXA, 200, rt * 16, ks * 32);
#pragma unroll
            for (int c2 = 0; c2 < 2; ++c2)
#pragma unroll
                for (int ks = 0; ks < 6; ++ks)
                    acc[rt][c2] = MF(af[ks], wf[c2][ks], acc[rt][c2]);
        }
#pragma unroll
        for (int c2 = 0; c2 < 2; ++c2) {
            float bv = qb[h * 32 + c2 * 16 + mcol];
#pragma unroll
            for (int rt = 0; rt < 4; ++rt)
#pragma unroll
                for (int j = 0; j < 4; ++j)
                    st[(rt * 16 + (g << 2) + j) * 40 + c2 * 16 + mcol] =
                        f2bf((acc[rt][c2][j] + bv) * SCALE);
        }
        asm volatile("s_waitcnt lgkmcnt(0)" ::: "memory");
#pragma unroll
        for (int rt = 0; rt < 4; ++rt) {
            bf16x8 fr = frag(st, 40, rt * 16, 0);
            *(bf16x8*)(Qf + ((size_t)(b * 6 + h) * 4 + rt) * 512 + lane * 8) = fr;
        }
        asm volatile("s_waitcnt lgkmcnt(0)" ::: "memory");
    }
}

// ---------------- Kernel B: attention + LAM + output projection ----------------
__global__ __launch_bounds__(384, 3) void attn_lam(
    const ushort* __restrict__ Qf, const ushort* __restrict__ Kf,
    const ushort* __restrict__ Vf, const ushort* __restrict__ cmb,
    const float* __restrict__ x1, const float* __restrict__ gammap,
    const ushort* __restrict__ pwbf, const float* __restrict__ pb,
    float* __restrict__ out)
{
    __shared__ __align__(16) ushort sPF[15360];   // P staging [6][64][40] / finalX [64][200]
    __shared__ __align__(16) ushort sY[13824];    // Y [6][32][72]
    __shared__ __align__(16) float  sE[32 * 33];
    __shared__ __align__(16) ushort sAtt[32 * 40];

    const int tid = threadIdx.x, wave = tid >> 6, lane = tid & 63;
    const int g = lane >> 4, mcol = lane & 15;
    const int b = blockIdx.x;
    const float gamma = gammap[0];
    const f32x4 zero4 = {0.f, 0.f, 0.f, 0.f};

    // B5: per-head attention (wave = head, 6 waves, all busy)
    {
        const int h = wave;
        const ushort* qp = Qf + (size_t)(b * 6 + h) * 2048;
        const ushort* kp = Kf + (size_t)(b * 6 + h) * 2048;
        const ushort* vp = Vf + (size_t)(b * 6 + h) * 2048;
        bf16x8 qa[4], kb[4];
#pragma unroll
        for (int rt = 0; rt < 4; ++rt) qa[rt] = *(const bf16x8*)(qp + rt * 512 + lane * 8);
#pragma unroll
        for (int ct = 0; ct < 4; ++ct) kb[ct] = *(const bf16x8*)(kp + ct * 512 + lane * 8);
        f32x4 acc[4][4];
#pragma unroll
        for (int rt = 0; rt < 4; ++rt)
#pragma unroll
            for (int ct = 0; ct < 4; ++ct)
                acc[rt][ct] = MF(qa[rt], kb[ct], zero4);
        // bias + mask (precombined bf16 table)
        const ushort* cp = cmb + (size_t)((b & 63) * 6 + h) * 4096;
#pragma unroll
        for (int rt = 0; rt < 4; ++rt)
#pragma unroll
            for (int ct = 0; ct < 4; ++ct) {
                ushort4 b4 = *(const ushort4*)(cp + (ct * 16 + mcol) * 64 + rt * 16 + (g << 2));
#pragma unroll
                for (int j = 0; j < 4; ++j) acc[rt][ct][j] += bf2f(((ushort*)&b4)[j]);
            }
        // row softmax
        float sm[4][4];
#pragma unroll
        for (int rt = 0; rt < 4; ++rt)
#pragma unroll
            for (int j = 0; j < 4; ++j) {
                float v = fmaxf(fmaxf(acc[rt][0][j], acc[rt][1][j]),
                                fmaxf(acc[rt][2][j], acc[rt][3][j]));
                v = fmaxf(v, __shfl_xor(v, 1, 64));
                v = fmaxf(v, __shfl_xor(v, 2, 64));
                v = fmaxf(v, __shfl_xor(v, 4, 64));
                v = fmaxf(v, __shfl_xor(v, 8, 64));
                float s = 0.f;
#pragma unroll
                for (int ct = 0; ct < 4; ++ct) {
                    float p = __expf(acc[rt][ct][j] - v);
                    acc[rt][ct][j] = p; s += p;
                }
                s += __shfl_xor(s, 1, 64);
                s += __shfl_xor(s, 2, 64);
                s += __shfl_xor(s, 4, 64);
                s += __shfl_xor(s, 8, 64);
                sm[rt][j] = 1.0f / s;
            }
        // PV
        ushort* Ph = sPF + h * 2560;
        f32x4 accy[4][2];
#pragma unroll
        for (int rt = 0; rt < 4; ++rt)
#pragma unroll
            for (int ctd = 0; ctd < 2; ++ctd) accy[rt][ctd] = zero4;
#pragma unroll
        for (int c = 0; c < 2; ++c) {
#pragma unroll
            for (int rt = 0; rt < 4; ++rt)
#pragma unroll
                for (int dct = 0; dct < 2; ++dct)
#pragma unroll
                    for (int j = 0; j < 4; ++j)
                        Ph[(rt * 16 + (g << 2) + j) * 40 + dct * 16 + mcol] =
                            f2bf(acc[rt][2 * c + dct][j]);
            asm volatile("s_waitcnt lgkmcnt(0)" ::: "memory");
#pragma unroll
            for (int rt = 0; rt < 4; ++rt) {
                bf16x8 pa = frag(Ph, 40, rt * 16, 0);
#pragma unroll
                for (int ctd = 0; ctd < 2; ++ctd) {
                    bf16x8 vb = *(const bf16x8*)(vp + (c * 2 + ctd) * 512 + lane * 8);
                    accy[rt][ctd] = MF(pa, vb, accy[rt][ctd]);
                }
            }
            asm volatile("s_waitcnt lgkmcnt(0)" ::: "memory");
        }
        // normalize, write Y [d][n]
        ushort* Yh = sY + h * 2304;
#pragma unroll
        for (int rt = 0; rt < 4; ++rt)
#pragma unroll
            for (int ctd = 0; ctd < 2; ++ctd) {
                int d = ctd * 16 + mcol;
                int n0 = rt * 16 + (g << 2);
                ushort4 w4;
#pragma unroll
                for (int j = 0; j < 4; ++j)
                    ((ushort*)&w4)[j] = f2bf(accy[rt][ctd][j] * sm[rt][j]);
                *(ushort4*)(&Yh[d * 72 + n0]) = w4;
            }
    }
    __syncthreads();

    // B6: LAM energy = flat @ flat^T [32x32], K=384 (waves 0-3)
    if (wave < 4) {
        int rt = wave >> 1, ct = wave & 1;
        f32x4 acc = zero4;
        for (int h = 0; h < 6; ++h) {
            const ushort* Yh = sY + h * 2304;
#pragma unroll
            for (int kk = 0; kk < 2; ++kk)
                acc = MF(frag(Yh, 72, rt * 16, kk * 32), frag(Yh, 72, ct * 16, kk * 32), acc);
        }
#pragma unroll
        for (int j = 0; j < 4; ++j)
            sE[(rt * 16 + (g << 2) + j) * 33 + ct * 16 + mcol] = acc[j];
    }
    __syncthreads();

    // B7: softmax rows of energy -> att bf16 (32 rows x 8 lanes)
    if (tid < 256) {
        int r = tid >> 3, l8 = tid & 7;
        float e[4];
        float mx = -1e30f;
#pragma unroll
        for (int k = 0; k < 4; ++k) { e[k] = sE[r * 33 + l8 + k * 8]; mx = fmaxf(mx, e[k]); }
        mx = fmaxf(mx, __shfl_xor(mx, 1, 64));
        mx = fmaxf(mx, __shfl_xor(mx, 2, 64));
        mx = fmaxf(mx, __shfl_xor(mx, 4, 64));
        float s = 0.f;
#pragma unroll
        for (int k = 0; k < 4; ++k) { e[k] = __expf(e[k] - mx); s += e[k]; }
        s += __shfl_xor(s, 1, 64);
        s += __shfl_xor(s, 2, 64);
        s += __shfl_xor(s, 4, 64);
        float rs = 1.0f / s;
#pragma unroll
        for (int k = 0; k < 4; ++k) sAtt[r * 40 + l8 + k * 8] = f2bf(e[k] * rs);
    }
    __syncthreads();

    // B8: outm = att @ flat; finalX = gamma*outm + flat + (q̂ + x1) -> sPF
    for (int t = wave; t < 48; t += 6) {
        int rtL = t & 1, ct = t >> 1;
        int col = ct * 16 + mcol;
        int hh = col >> 6, nn = col & 63;
        const ushort* Yh = sY + hh * 2304;
        bf16x8 aa = frag(sAtt, 40, rtL * 16, 0);
        bf16x8 bb;
#pragma unroll
        for (int jj = 0; jj < 8; ++jj) bb[jj] = (short)Yh[((g << 3) + jj) * 72 + nn];
        f32x4 acc = MF(aa, bb, zero4);
        int d0 = rtL * 16 + (g << 2);
        ushort4 qv4 = *(const ushort4*)(Qf + (size_t)(b * 6 + hh) * 2048 +
                                        (nn >> 4) * 512 + ((nn & 15) + ((d0 >> 3) << 4)) * 8 + (d0 & 7));
        float4 xv4 = *(const float4*)(x1 + (size_t)b * 12288 + nn * 192 + hh * 32 + d0);
        ushort4 w4;
#pragma unroll
        for (int j = 0; j < 4; ++j) {
            float flatv = bf2f(Yh[(d0 + j) * 72 + nn]);
            float val = gamma * acc[j] + flatv + bf2f(((ushort*)&qv4)[j]) + ((const float*)&xv4)[j];
            ((ushort*)&w4)[j] = f2bf(val);
        }
        *(ushort4*)(&sPF[nn * 200 + hh * 32 + d0]) = w4;
    }
    __syncthreads();

    // B9: out = finalX @ pw^T + pb
    {
        float* outp = out + (size_t)b * 12288;
        for (int i = 0; i < 8; ++i) {
            int idx = wave * 8 + i;
            int rt = idx / 12, ct = idx - rt * 12;
            bf16x8 af[6];
#pragma unroll
            for (int ks = 0; ks < 6; ++ks) af[ks] = frag(sPF, 200, rt * 16, ks * 32);
            f32x4 acc = zero4;
#pragma unroll
            for (int ks = 0; ks < 6; ++ks)
                acc = MF(af[ks], frag(pwbf, DIM, ct * 16, ks * 32), acc);
            int co = ct * 16 + mcol;
            float pbv = pb[co];
#pragma unroll
            for (int j = 0; j < 4; ++j)
                outp[(rt * 16 + (g << 2) + j) * DIM + co] = acc[j] + pbv;
        }
    }
}

// ---------------- Fallback: previous single fused kernel (passing) ----------------
__global__ __launch_bounds__(512, 2) void fused_win_attn(
    const float* __restrict__ x1, const float* __restrict__ x2,
    const float* __restrict__ mask, const float* __restrict__ qb,
    const float* __restrict__ kvb, const float* __restrict__ rpb,
    const float* __restrict__ gammap, const float* __restrict__ pb,
    const ushort* __restrict__ qwbf, const ushort* __restrict__ kvwbf,
    const ushort* __restrict__ pwbf, float* __restrict__ out)
{
    __shared__ __align__(16) ushort sX[64 * 200];
    __shared__ __align__(16) ushort sQP[6 * 64 * 40];
    __shared__ __align__(16) ushort sK[6 * 64 * 40];
    __shared__ __align__(16) ushort sVY[6 * 32 * 72];
    __shared__ __align__(16) ushort sR[64 * 192];
    __shared__ __align__(16) ushort sRPB[1352];

    const int tid  = threadIdx.x;
    const int wave = tid >> 6;
    const int lane = tid & 63;
    const int g    = lane >> 4;
    const int mcol = lane & 15;
    const int b    = blockIdx.x;
    const float gamma = gammap[0];

    for (int i = tid; i < 1350; i += 512) sRPB[i] = f2bf(rpb[i]);
    {
        const float4* src = (const float4*)(x2 + (size_t)b * (NTOK * DIM));
        for (int i = tid; i < 3072; i += 512) {
            float4 v = src[i];
            int e = i << 2; int n = e / DIM; int c = e - n * DIM;
            ushort4 w; w.x = f2bf(v.x); w.y = f2bf(v.y); w.z = f2bf(v.z); w.w = f2bf(v.w);
            *(ushort4*)(&sX[n * 200 + c]) = w;
        }
    }
    __syncthreads();
    {
        const int rt = wave & 3;
        bf16x8 af[6];
#pragma unroll
        for (int ks = 0; ks < 6; ++ks) af[ks] = frag(sX, 200, rt * 16, ks * 32);
        for (int ct = (wave >> 2); ct < 24; ct += 2) {
            f32x4 acc = {0.f, 0.f, 0.f, 0.f};
#pragma unroll
            for (int ks = 0; ks < 6; ++ks)
                acc = MF(af[ks], frag(kvwbf, DIM, ct * 16, ks * 32), acc);
            int co = ct * 16 + mcol;
            float bv = kvb[co];
            int r0 = rt * 16 + (g << 2);
            if (co < DIM) {
                int h = co >> 5, d = co & 31;
                ushort* dst = sK + h * (64 * 40);
#pragma unroll
                for (int j = 0; j < 4; ++j) dst[(r0 + j) * 40 + d] = f2bf(acc[j] + bv);
            } else {
                int cv = co - DIM; int h = cv >> 5, d = cv & 31;
                ushort4 w4;
#pragma unroll
                for (int j = 0; j < 4; ++j) ((ushort*)&w4)[j] = f2bf(acc[j] + bv);
                *(ushort4*)(&sVY[h * (32 * 72) + d * 72 + r0]) = w4;
            }
        }
    }
    __syncthreads();
    {
        const float4* src = (const float4*)(x1 + (size_t)b * (NTOK * DIM));
        for (int i = tid; i < 3072; i += 512) {
            float4 v = src[i];
            int e = i << 2; int n = e / DIM; int c = e - n * DIM;
            ushort4 w; w.x = f2bf(v.x); w.y = f2bf(v.y); w.z = f2bf(v.z); w.w = f2bf(v.w);
            *(ushort4*)(&sX[n * 200 + c]) = w;
        }
    }
    __syncthreads();
    {
        const int rt = wave & 3;
        bf16x8 af[6];
#pragma unroll
        for (int ks = 0; ks < 6; ++ks) af[ks] = frag(sX, 200, rt * 16, ks * 32);
        for (int ct = (wave >> 2); ct < 12; ct += 2) {
            f32x4 acc = {0.f, 0.f, 0.f, 0.f};
#pragma unroll
            for (int ks = 0; ks < 6; ++ks)
                acc = MF(af[ks], frag(qwbf, DIM, ct * 16, ks * 32), acc);
            int co = ct * 16 + mcol;
            float bv = qb[co];
            int h = co >> 5, d = co & 31;
            int r0 = rt * 16 + (g << 2);
            ushort* dq = sQP + h * (64 * 40);
#pragma unroll
            for (int j = 0; j < 4; ++j) {
                float qv = (acc[j] + bv) * SCALE;
                dq[(r0 + j) * 40 + d] = f2bf(qv);
                float xv = bf2f(sX[(r0 + j) * 200 + co]);
                sR[(r0 + j) * DIM + co] = f2bf(qv + xv);
            }
        }
    }
    __syncthreads();
    if (wave < NHEAD) {
        const int h = wave;
        const ushort* Qh = sQP + h * (64 * 40);
        const ushort* Kh = sK  + h * (64 * 40);
        f32x4 acc[4][4];
        bf16x8 qa[4], kb[4];
#pragma unroll
        for (int rt = 0; rt < 4; ++rt) qa[rt] = frag(Qh, 40, rt * 16, 0);
#pragma unroll
        for (int ct = 0; ct < 4; ++ct) kb[ct] = frag(Kh, 40, ct * 16, 0);
        f32x4 zero4 = {0.f, 0.f, 0.f, 0.f};
#pragma unroll
        for (int rt = 0; rt < 4; ++rt)
#pragma unroll
            for (int ct = 0; ct < 4; ++ct)
                acc[rt][ct] = MF(qa[rt], kb[ct], zero4);
        const float* mp = mask + (size_t)(b & 63) * 4096;
#pragma unroll
        for (int rt = 0; rt < 4; ++rt)
#pragma unroll
            for (int ct = 0; ct < 4; ++ct)
#pragma unroll
                for (int j = 0; j < 4; ++j) {
                    int n = rt * 16 + (g << 2) + j;
                    int m = ct * 16 + mcol;
                    int ridx = ((n >> 3) - (m >> 3) + 7) * 15 + ((n & 7) - (m & 7) + 7);
                    acc[rt][ct][j] += bf2f(sRPB[ridx * 6 + h]) + mp[n * 64 + m];
                }
        float sm[4][4];
#pragma unroll
        for (int rt = 0; rt < 4; ++rt)
#pragma unroll
            for (int j = 0; j < 4; ++j) {
                float v = fmaxf(fmaxf(acc[rt][0][j], acc[rt][1][j]),
                                fmaxf(acc[rt][2][j], acc[rt][3][j]));
                v = fmaxf(v, __shfl_xor(v, 1, 64));
                v = fmaxf(v, __shfl_xor(v, 2, 64));
                v = fmaxf(v, __shfl_xor(v, 4, 64));
                v = fmaxf(v, __shfl_xor(v, 8, 64));
                float s = 0.f;
#pragma unroll
                for (int ct = 0; ct < 4; ++ct) {
                    float p = __expf(acc[rt][ct][j] - v);
                    acc[rt][ct][j] = p; s += p;
                }
                s += __shfl_xor(s, 1, 64);
                s += __shfl_xor(s, 2, 64);
                s += __shfl_xor(s, 4, 64);
                s += __shfl_xor(s, 8, 64);
                sm[rt][j] = 1.0f / s;
            }
        ushort* Ph = sQP + h * (64 * 40);
        const ushort* Vh = sVY + h * (32 * 72);
        f32x4 accy[4][2];
#pragma unroll
        for (int rt = 0; rt < 4; ++rt)
#pragma unroll
            for (int ctd = 0; ctd < 2; ++ctd) accy[rt][ctd] = zero4;
#pragma unroll
        for (int c = 0; c < 2; ++c) {
#pragma unroll
            for (int rt = 0; rt < 4; ++rt)
#pragma unroll
                for (int dct = 0; dct < 2; ++dct)
#pragma unroll
                    for (int j = 0; j < 4; ++j) {
                        int row = rt * 16 + (g << 2) + j;
                        Ph[row * 40 + dct * 16 + mcol] = f2bf(acc[rt][2 * c + dct][j]);
                    }
            asm volatile("s_waitcnt lgkmcnt(0)" ::: "memory");
#pragma unroll
            for (int rt = 0; rt < 4; ++rt) {
                bf16x8 pa = frag(Ph, 40, rt * 16, 0);
#pragma unroll
                for (int ctd = 0; ctd < 2; ++ctd) {
                    bf16x8 vb = frag(Vh, 72, ctd * 16, c * 32);
                    accy[rt][ctd] = MF(pa, vb, accy[rt][ctd]);
                }
            }
            asm volatile("s_waitcnt lgkmcnt(0)" ::: "memory");
        }
        ushort* Yh = sVY + h * (32 * 72);
#pragma unroll
        for (int rt = 0; rt < 4; ++rt)
#pragma unroll
            for (int ctd = 0; ctd < 2; ++ctd) {
                int d = ctd * 16 + mcol;
                int n0 = rt * 16 + (g << 2);
                ushort4 w4;
#pragma unroll
                for (int j = 0; j < 4; ++j)
                    ((ushort*)&w4)[j] = f2bf(accy[rt][ctd][j] * sm[rt][j]);
                *(ushort4*)(&Yh[d * 72 + n0]) = w4;
            }
    }
    __syncthreads();
    float*  sE   = (float*)sK;
    ushort* sAtt = sK + 2112;
    if (wave < 4) {
        int rt = wave >> 1, ct = wave & 1;
        f32x4 acc = {0.f, 0.f, 0.f, 0.f};
        for (int h = 0; h < 6; ++h) {
            const ushort* Yh = sVY + h * (32 * 72);
#pragma unroll
            for (int kk = 0; kk < 2; ++kk) {
                bf16x8 a  = frag(Yh, 72, rt * 16, kk * 32);
                bf16x8 bb = frag(Yh, 72, ct * 16, kk * 32);
                acc = MF(a, bb, acc);
            }
        }
#pragma unroll
        for (int j = 0; j < 4; ++j) {
            int i = rt * 16 + (g << 2) + j;
            sE[i * 33 + ct * 16 + mcol] = acc[j];
        }
    }
    __syncthreads();
    if (tid < 32) {
        int r = tid;
        float mx = -1e30f;
#pragma unroll
        for (int j = 0; j < 32; ++j) mx = fmaxf(mx, sE[r * 33 + j]);
        float s = 0.f;
        float ev[32];
#pragma unroll
        for (int j = 0; j < 32; ++j) { ev[j] = __expf(sE[r * 33 + j] - mx); s += ev[j]; }
        float rs = 1.0f / s;
#pragma unroll
        for (int j = 0; j < 32; ++j) sAtt[r * 40 + j] = f2bf(ev[j] * rs);
    }
    __syncthreads();
    for (int t = wave; t < 48; t += 8) {
        int rt = t & 1, ct = t >> 1;
        int col = ct * 16 + mcol;
        int hh = col >> 6, nn = col & 63;
        const ushort* Yh = sVY + hh * (32 * 72);
        bf16x8 aa = frag(sAtt, 40, rt * 16, 0);
        bf16x8 bb;
#pragma unroll
        for (int jj = 0; jj < 8; ++jj) bb[jj] = (short)Yh[((g << 3) + jj) * 72 + nn];
        f32x4 zero4 = {0.f, 0.f, 0.f, 0.f};
        f32x4 acc = MF(aa, bb, zero4);
        ushort4 w4;
#pragma unroll
        for (int j = 0; j < 4; ++j) {
            int d = rt * 16 + (g << 2) + j;
            float flatv = bf2f(Yh[d * 72 + nn]);
            float val = gamma * acc[j] + flatv;
            float rv = bf2f(sR[nn * DIM + hh * 32 + d]);
            ((ushort*)&w4)[j] = f2bf(val + rv);
        }
        *(ushort4*)(&sX[nn * 200 + hh * 32 + rt * 16 + (g << 2)]) = w4;
    }
    __syncthreads();
    {
        float* outp = out + (size_t)b * (NTOK * DIM);
        const int rt = wave & 3;
        bf16x8 af[6];
#pragma unroll
        for (int ks = 0; ks < 6; ++ks) af[ks] = frag(sX, 200, rt * 16, ks * 32);
        for (int ct = (wave >> 2); ct < 12; ct += 2) {
            f32x4 acc = {0.f, 0.f, 0.f, 0.f};
#pragma unroll
            for (int ks = 0; ks < 6; ++ks)
                acc = MF(af[ks], frag(pwbf, DIM, ct * 16, ks * 32), acc);
            int co = ct * 16 + mcol;
            float pbv = pb[co];
#pragma unroll
            for (int j = 0; j < 4; ++j) {
                int n = rt * 16 + (g << 2) + j;
                outp[n * DIM + co] = acc[j] + pbv;
            }
        }
    }
}

extern "C" void kernel_launch(void* const* d_in, const int* in_sizes, int n_in,
                              void* d_out, int out_size, void* d_ws, size_t ws_size,
                              hipStream_t stream) {
    const float* x1    = (const float*)d_in[0];
    const float* x2    = (const float*)d_in[1];
    const float* mask  = (const float*)d_in[2];
    const float* qw    = (const float*)d_in[3];
    const float* qbv   = (const float*)d_in[4];
    const float* kvw   = (const float*)d_in[5];
    const float* kvbv  = (const float*)d_in[6];
    const float* rpb   = (const float*)d_in[7];
    const float* gamma = (const float*)d_in[8];
    const float* pw    = (const float*)d_in[9];
    const float* pbv   = (const float*)d_in[10];
    ushort* wbf = (ushort*)d_ws;   // qw_bf | kvw_bf | pw_bf

    prep_weights<<<576, 256, 0, stream>>>(qw, kvw, pw, wbf);

    const size_t NEED = 154435584;   // bytes: weights + cmb + Qf + Kf + Vf
    if (ws_size >= NEED) {
        ushort* cmb = wbf + 147456;
        ushort* Qf  = wbf + 1720320;
        ushort* Kf  = wbf + 26886144;
        ushort* Vf  = wbf + 52051968;
        prep_cmb<<<1536, 256, 0, stream>>>(rpb, mask, cmb);
        proj_qkv<<<2048, 256, 0, stream>>>(x1, x2, qbv, kvbv,
                                           wbf, wbf + 36864, Qf, Kf, Vf);
        attn_lam<<<2048, 384, 0, stream>>>(Qf, Kf, Vf, cmb, x1, gamma,
                                           wbf + 110592, pbv, (float*)d_out);
    } else {
        fused_win_attn<<<2048, 512, 0, stream>>>(x1, x2, mask, qbv, kvbv, rpb, gamma, pbv,
                                                 wbf, wbf + 36864, wbf + 110592,
                                                 (float*)d_out);
    }
}

// Round 3
// 326.778 us; speedup vs baseline: 1.2964x; 1.0187x over previous
//
#include <hip/hip_runtime.h>

#define DIM 192
#define NTOK 64
#define NHEAD 6
#define HDIM 32
#define SCALE 0.17677669529663687f

typedef __attribute__((ext_vector_type(8))) short bf16x8;
typedef __attribute__((ext_vector_type(4))) float f32x4;

__device__ __forceinline__ ushort f2bf(float f) {
    union { float f; unsigned u; } x; x.f = f;
    unsigned r = x.u + 0x7FFFu + ((x.u >> 16) & 1u);
    return (ushort)(r >> 16);
}
__device__ __forceinline__ float bf2f(ushort h) {
    union { unsigned u; float f; } x; x.u = ((unsigned)h) << 16;
    return x.f;
}

__device__ __forceinline__ f32x4 MF(bf16x8 a, bf16x8 b, f32x4 c) {
    return __builtin_amdgcn_mfma_f32_16x16x32_bf16(a, b, c, 0, 0, 0);
}

// A/B fragment load for 16x16x32 bf16 mfma from a row-major bf16 matrix.
__device__ __forceinline__ bf16x8 frag(const ushort* base, int stride, int r0, int k0) {
    const int l = threadIdx.x & 63;
    return *(const bf16x8*)(base + (r0 + (l & 15)) * stride + (k0 + ((l >> 4) << 3)));
}

__global__ void prep_weights(const float* __restrict__ qw, const float* __restrict__ kvw,
                             const float* __restrict__ pw, ushort* __restrict__ wbf) {
    int i = blockIdx.x * 256 + threadIdx.x;
    if (i < 36864) wbf[i] = f2bf(qw[i]);
    else if (i < 110592) wbf[i] = f2bf(kvw[i - 36864]);
    else if (i < 147456) wbf[i] = f2bf(pw[i - 110592]);
}

// cmb[w][h][m][n] = rpb_bias(h,n,m) + mask[w][n][m]   (bf16)
__global__ void prep_cmb(const float* __restrict__ rpb, const float* __restrict__ mask,
                         ushort* __restrict__ cmb) {
    int t = blockIdx.x * 256 + threadIdx.x;
    int e = t << 2;
    int n0 = e & 63;
    int m  = (e >> 6) & 63;
    int hw = e >> 12;
    int h = hw % 6, w = hw / 6;
#pragma unroll
    for (int j = 0; j < 4; ++j) {
        int n = n0 + j;
        int ridx = ((n >> 3) - (m >> 3) + 7) * 15 + ((n & 7) - (m & 7) + 7);
        float v = rpb[ridx * 6 + h] + mask[(w * 64 + n) * 64 + m];
        cmb[e + j] = f2bf(v);
    }
}

// ---------------- Kernel A: projections -> fragment-linear Q/K/V ----------------
__global__ __launch_bounds__(256, 3) void proj_qkv(
    const float* __restrict__ x1, const float* __restrict__ x2,
    const float* __restrict__ qb, const float* __restrict__ kvb,
    const ushort* __restrict__ qwbf, const ushort* __restrict__ kvwbf,
    ushort* __restrict__ Qf, ushort* __restrict__ Kf, ushort* __restrict__ Vf)
{
    __shared__ __align__(16) ushort sXA[64 * 200];
    __shared__ __align__(16) ushort stg[4 * 2560];
    const int tid = threadIdx.x, wave = tid >> 6, lane = tid & 63;
    const int g = lane >> 4, mcol = lane & 15;
    const int b = blockIdx.x;
    ushort* st = stg + wave * 2560;

    {
        const float4* src = (const float4*)(x2 + (size_t)b * 12288);
        for (int i = tid; i < 3072; i += 256) {
            float4 v = src[i];
            int e = i << 2; int n = e / DIM; int c = e - n * DIM;
            ushort4 w;
            ((ushort*)&w)[0] = f2bf(v.x); ((ushort*)&w)[1] = f2bf(v.y);
            ((ushort*)&w)[2] = f2bf(v.z); ((ushort*)&w)[3] = f2bf(v.w);
            *(ushort4*)(&sXA[n * 200 + c]) = w;
        }
    }
    __syncthreads();

    for (int t = wave; t < 12; t += 4) {
        const int isV = (t >= 6) ? 1 : 0;
        const int h = isV ? (t - 6) : t;
        bf16x8 wf[2][6];
#pragma unroll
        for (int c2 = 0; c2 < 2; ++c2) {
            int ctg = (isV ? (12 + 2 * h) : (2 * h)) + c2;
#pragma unroll
            for (int ks = 0; ks < 6; ++ks)
                wf[c2][ks] = frag(kvwbf, DIM, ctg * 16, ks * 32);
        }
        f32x4 acc[4][2];
#pragma unroll
        for (int rt = 0; rt < 4; ++rt)
#pragma unroll
            for (int c2 = 0; c2 < 2; ++c2) acc[rt][c2] = (f32x4){0.f, 0.f, 0.f, 0.f};
#pragma unroll
        for (int rt = 0; rt < 4; ++rt) {
            bf16x8 af[6];
#pragma unroll
            for (int ks = 0; ks < 6; ++ks) af[ks] = frag(sXA, 200, rt * 16, ks * 32);
#pragma unroll
            for (int c2 = 0; c2 < 2; ++c2)
#pragma unroll
                for (int ks = 0; ks < 6; ++ks)
                    acc[rt][c2] = MF(af[ks], wf[c2][ks], acc[rt][c2]);
        }
        if (!isV) {
#pragma unroll
            for (int c2 = 0; c2 < 2; ++c2) {
                float bv = kvb[h * 32 + c2 * 16 + mcol];
#pragma unroll
                for (int rt = 0; rt < 4; ++rt)
#pragma unroll
                    for (int j = 0; j < 4; ++j)
                        st[(rt * 16 + (g << 2) + j) * 40 + c2 * 16 + mcol] = f2bf(acc[rt][c2][j] + bv);
            }
            asm volatile("s_waitcnt lgkmcnt(0)" ::: "memory");
#pragma unroll
            for (int ct = 0; ct < 4; ++ct) {
                bf16x8 fr = frag(st, 40, ct * 16, 0);
                *(bf16x8*)(Kf + ((size_t)(b * 6 + h) * 4 + ct) * 512 + lane * 8) = fr;
            }
            asm volatile("s_waitcnt lgkmcnt(0)" ::: "memory");
        } else {
#pragma unroll
            for (int c2 = 0; c2 < 2; ++c2) {
                float bv = kvb[192 + h * 32 + c2 * 16 + mcol];
#pragma unroll
                for (int rt = 0; rt < 4; ++rt) {
                    ushort4 w4;
#pragma unroll
                    for (int j = 0; j < 4; ++j) ((ushort*)&w4)[j] = f2bf(acc[rt][c2][j] + bv);
                    *(ushort4*)(&st[(c2 * 16 + mcol) * 72 + rt * 16 + (g << 2)]) = w4;
                }
            }
            asm volatile("s_waitcnt lgkmcnt(0)" ::: "memory");
#pragma unroll
            for (int c = 0; c < 2; ++c)
#pragma unroll
                for (int ctd = 0; ctd < 2; ++ctd) {
                    bf16x8 fr = frag(st, 72, ctd * 16, c * 32);
                    *(bf16x8*)(Vf + (((size_t)(b * 6 + h) * 2 + c) * 2 + ctd) * 512 + lane * 8) = fr;
                }
            asm volatile("s_waitcnt lgkmcnt(0)" ::: "memory");
        }
    }
    __syncthreads();

    {
        const float4* src = (const float4*)(x1 + (size_t)b * 12288);
        for (int i = tid; i < 3072; i += 256) {
            float4 v = src[i];
            int e = i << 2; int n = e / DIM; int c = e - n * DIM;
            ushort4 w;
            ((ushort*)&w)[0] = f2bf(v.x); ((ushort*)&w)[1] = f2bf(v.y);
            ((ushort*)&w)[2] = f2bf(v.z); ((ushort*)&w)[3] = f2bf(v.w);
            *(ushort4*)(&sXA[n * 200 + c]) = w;
        }
    }
    __syncthreads();

    for (int t = wave; t < 6; t += 4) {
        const int h = t;
        bf16x8 wf[2][6];
#pragma unroll
        for (int c2 = 0; c2 < 2; ++c2)
#pragma unroll
            for (int ks = 0; ks < 6; ++ks)
                wf[c2][ks] = frag(qwbf, DIM, (2 * h + c2) * 16, ks * 32);
        f32x4 acc[4][2];
#pragma unroll
        for (int rt = 0; rt < 4; ++rt)
#pragma unroll
            for (int c2 = 0; c2 < 2; ++c2) acc[rt][c2] = (f32x4){0.f, 0.f, 0.f, 0.f};
#pragma unroll
        for (int rt = 0; rt < 4; ++rt) {
            bf16x8 af[6];
#pragma unroll
            for (int ks = 0; ks < 6; ++ks) af[ks] = frag(sXA, 200, rt * 16, ks * 32);
#pragma unroll
            for (int c2 = 0; c2 < 2; ++c2)
#pragma unroll
                for (int ks = 0; ks < 6; ++ks)
                    acc[rt][c2] = MF(af[ks], wf[c2][ks], acc[rt][c2]);
        }
#pragma unroll
        for (int c2 = 0; c2 < 2; ++c2) {
            float bv = qb[h * 32 + c2 * 16 + mcol];
#pragma unroll
            for (int rt = 0; rt < 4; ++rt)
#pragma unroll
                for (int j = 0; j < 4; ++j)
                    st[(rt * 16 + (g << 2) + j) * 40 + c2 * 16 + mcol] =
                        f2bf((acc[rt][c2][j] + bv) * SCALE);
        }
        asm volatile("s_waitcnt lgkmcnt(0)" ::: "memory");
#pragma unroll
        for (int rt = 0; rt < 4; ++rt) {
            bf16x8 fr = frag(st, 40, rt * 16, 0);
            *(bf16x8*)(Qf + ((size_t)(b * 6 + h) * 4 + rt) * 512 + lane * 8) = fr;
        }
        asm volatile("s_waitcnt lgkmcnt(0)" ::: "memory");
    }
}

// ---------------- Kernel B: attention + LAM + output projection (v3) ----------------
// LDS 37.5KB (4 blocks/CU target), rt-sliced attention for low VGPR.
__global__ __launch_bounds__(384, 6) void attn_lam(
    const ushort* __restrict__ Qf, const ushort* __restrict__ Kf,
    const ushort* __restrict__ Vf, const ushort* __restrict__ cmb,
    const float* __restrict__ x1, const float* __restrict__ gammap,
    const ushort* __restrict__ pwbf, const float* __restrict__ pb,
    float* __restrict__ out)
{
    // per-head slot (2560 ush): P-slice [16][72] -> Y [32][72]; later finalX [64][200]
    __shared__ __align__(16) ushort sPY[6 * 2560];
    __shared__ __align__(16) float  sE[32 * 33];
    __shared__ __align__(16) ushort sAtt[32 * 40];

    const int tid = threadIdx.x, wave = tid >> 6, lane = tid & 63;
    const int g = lane >> 4, mcol = lane & 15;
    const int b = blockIdx.x;
    const float gamma = gammap[0];
    const f32x4 zero4 = {0.f, 0.f, 0.f, 0.f};

    // ---- B5: per-head attention, rt-sliced (wave = head) ----
    {
        const int h = wave;
        const ushort* qp = Qf + (size_t)(b * 6 + h) * 2048;
        const ushort* kp = Kf + (size_t)(b * 6 + h) * 2048;
        const ushort* vp = Vf + (size_t)(b * 6 + h) * 2048;
        const ushort* cp = cmb + (size_t)((b & 63) * 6 + h) * 4096;
        ushort* slot = sPY + h * 2560;

        bf16x8 kb[4];
#pragma unroll
        for (int ct = 0; ct < 4; ++ct) kb[ct] = *(const bf16x8*)(kp + ct * 512 + lane * 8);

        ushort4 y4[4][2];   // normalized Y (bf16), y4[rt][ctd]
#pragma unroll
        for (int rt = 0; rt < 4; ++rt) {
            bf16x8 qa = *(const bf16x8*)(qp + rt * 512 + lane * 8);
            f32x4 acc[4];
#pragma unroll
            for (int ct = 0; ct < 4; ++ct) acc[ct] = MF(qa, kb[ct], zero4);
#pragma unroll
            for (int ct = 0; ct < 4; ++ct) {
                ushort4 b4 = *(const ushort4*)(cp + (ct * 16 + mcol) * 64 + rt * 16 + (g << 2));
#pragma unroll
                for (int j = 0; j < 4; ++j) acc[ct][j] += bf2f(((ushort*)&b4)[j]);
            }
            // softmax over the 4 rows of this slice; pre-normalize P
            float sm[4];
#pragma unroll
            for (int j = 0; j < 4; ++j) {
                float v = fmaxf(fmaxf(acc[0][j], acc[1][j]), fmaxf(acc[2][j], acc[3][j]));
                v = fmaxf(v, __shfl_xor(v, 1, 64));
                v = fmaxf(v, __shfl_xor(v, 2, 64));
                v = fmaxf(v, __shfl_xor(v, 4, 64));
                v = fmaxf(v, __shfl_xor(v, 8, 64));
                float s = 0.f;
#pragma unroll
                for (int ct = 0; ct < 4; ++ct) {
                    float p = __expf(acc[ct][j] - v);
                    acc[ct][j] = p; s += p;
                }
                s += __shfl_xor(s, 1, 64);
                s += __shfl_xor(s, 2, 64);
                s += __shfl_xor(s, 4, 64);
                s += __shfl_xor(s, 8, 64);
                sm[j] = 1.0f / s;
            }
            // stage normalized P slice [16 rows][64 m] (stride 72)
#pragma unroll
            for (int ct = 0; ct < 4; ++ct)
#pragma unroll
                for (int j = 0; j < 4; ++j)
                    slot[((g << 2) + j) * 72 + ct * 16 + mcol] = f2bf(acc[ct][j] * sm[j]);
            asm volatile("s_waitcnt lgkmcnt(0)" ::: "memory");
            // PV for this slice
            f32x4 ay0 = zero4, ay1 = zero4;
#pragma unroll
            for (int c = 0; c < 2; ++c) {
                bf16x8 pa  = frag(slot, 72, 0, c * 32);
                bf16x8 vb0 = *(const bf16x8*)(vp + (c * 2 + 0) * 512 + lane * 8);
                bf16x8 vb1 = *(const bf16x8*)(vp + (c * 2 + 1) * 512 + lane * 8);
                ay0 = MF(pa, vb0, ay0);
                ay1 = MF(pa, vb1, ay1);
            }
            asm volatile("s_waitcnt lgkmcnt(0)" ::: "memory");   // pa reads done before overwrite
#pragma unroll
            for (int j = 0; j < 4; ++j) {
                ((ushort*)&y4[rt][0])[j] = f2bf(ay0[j]);
                ((ushort*)&y4[rt][1])[j] = f2bf(ay1[j]);
            }
        }
        // write Y [d][n] stride 72 into slot (P region fully dead)
#pragma unroll
        for (int rt = 0; rt < 4; ++rt)
#pragma unroll
            for (int ctd = 0; ctd < 2; ++ctd)
                *(ushort4*)(&slot[(ctd * 16 + mcol) * 72 + rt * 16 + (g << 2)]) = y4[rt][ctd];
    }
    __syncthreads();

    // ---- B6: LAM energy = flat @ flat^T [32x32], K=384 (waves 0-3, dual acc) ----
    if (wave < 4) {
        int rt = wave >> 1, ct = wave & 1;
        f32x4 a0 = zero4, a1 = zero4;
#pragma unroll
        for (int h = 0; h < 6; h += 2) {
            const ushort* Y0 = sPY + h * 2560;
            const ushort* Y1 = sPY + (h + 1) * 2560;
#pragma unroll
            for (int kk = 0; kk < 2; ++kk) {
                a0 = MF(frag(Y0, 72, rt * 16, kk * 32), frag(Y0, 72, ct * 16, kk * 32), a0);
                a1 = MF(frag(Y1, 72, rt * 16, kk * 32), frag(Y1, 72, ct * 16, kk * 32), a1);
            }
        }
        f32x4 acc = a0 + a1;
#pragma unroll
        for (int j = 0; j < 4; ++j)
            sE[(rt * 16 + (g << 2) + j) * 33 + ct * 16 + mcol] = acc[j];
    }
    __syncthreads();

    // ---- B7: softmax rows of energy -> att bf16 ----
    if (tid < 256) {
        int r = tid >> 3, l8 = tid & 7;
        float e[4];
        float mx = -1e30f;
#pragma unroll
        for (int k = 0; k < 4; ++k) { e[k] = sE[r * 33 + l8 + k * 8]; mx = fmaxf(mx, e[k]); }
        mx = fmaxf(mx, __shfl_xor(mx, 1, 64));
        mx = fmaxf(mx, __shfl_xor(mx, 2, 64));
        mx = fmaxf(mx, __shfl_xor(mx, 4, 64));
        float s = 0.f;
#pragma unroll
        for (int k = 0; k < 4; ++k) { e[k] = __expf(e[k] - mx); s += e[k]; }
        s += __shfl_xor(s, 1, 64);
        s += __shfl_xor(s, 2, 64);
        s += __shfl_xor(s, 4, 64);
        float rs = 1.0f / s;
#pragma unroll
        for (int k = 0; k < 4; ++k) sAtt[r * 40 + l8 + k * 8] = f2bf(e[k] * rs);
    }
    __syncthreads();

    // ---- B8: outm = att @ flat; finalX = gamma*outm + flat + (q̂ + x1) ----
    ushort4 w4st[8];
#pragma unroll
    for (int i = 0; i < 8; ++i) {
        int t = wave + i * 6;
        int rtL = t & 1, ct = t >> 1;
        int col = ct * 16 + mcol;
        int hh = col >> 6, nn = col & 63;
        const ushort* Yh = sPY + hh * 2560;
        bf16x8 aa = frag(sAtt, 40, rtL * 16, 0);
        bf16x8 bb;
#pragma unroll
        for (int jj = 0; jj < 8; ++jj) bb[jj] = (short)Yh[((g << 3) + jj) * 72 + nn];
        f32x4 acc = MF(aa, bb, zero4);
        int d0 = rtL * 16 + (g << 2);
        ushort4 qv4 = *(const ushort4*)(Qf + (size_t)(b * 6 + hh) * 2048 +
                                        (nn >> 4) * 512 + ((nn & 15) + ((d0 >> 3) << 4)) * 8 + (d0 & 7));
        float4 xv4 = *(const float4*)(x1 + (size_t)b * 12288 + nn * 192 + hh * 32 + d0);
        ushort4 w4;
#pragma unroll
        for (int j = 0; j < 4; ++j) {
            float flatv = bf2f(Yh[(d0 + j) * 72 + nn]);
            float val = gamma * acc[j] + flatv + bf2f(((ushort*)&qv4)[j]) + ((const float*)&xv4)[j];
            ((ushort*)&w4)[j] = f2bf(val);
        }
        w4st[i] = w4;
    }
    __syncthreads();   // all Y reads complete before finalX overwrites slots
#pragma unroll
    for (int i = 0; i < 8; ++i) {
        int t = wave + i * 6;
        int rtL = t & 1, ct = t >> 1;
        int col = ct * 16 + mcol;
        int hh = col >> 6, nn = col & 63;
        int d0 = rtL * 16 + (g << 2);
        *(ushort4*)(&sPY[nn * 200 + hh * 32 + d0]) = w4st[i];
    }
    __syncthreads();

    // ---- B9: out = finalX @ pw^T + pb ----
    {
        float* outp = out + (size_t)b * 12288;
        for (int i = 0; i < 8; ++i) {
            int idx = wave * 8 + i;
            int rt = idx / 12, ct = idx - rt * 12;
            bf16x8 af[6];
#pragma unroll
            for (int ks = 0; ks < 6; ++ks) af[ks] = frag(sPY, 200, rt * 16, ks * 32);
            f32x4 acc = zero4;
#pragma unroll
            for (int ks = 0; ks < 6; ++ks)
                acc = MF(af[ks], frag(pwbf, DIM, ct * 16, ks * 32), acc);
            int co = ct * 16 + mcol;
            float pbv = pb[co];
#pragma unroll
            for (int j = 0; j < 4; ++j)
                outp[(rt * 16 + (g << 2) + j) * DIM + co] = acc[j] + pbv;
        }
    }
}

extern "C" void kernel_launch(void* const* d_in, const int* in_sizes, int n_in,
                              void* d_out, int out_size, void* d_ws, size_t ws_size,
                              hipStream_t stream) {
    const float* x1    = (const float*)d_in[0];
    const float* x2    = (const float*)d_in[1];
    const float* mask  = (const float*)d_in[2];
    const float* qw    = (const float*)d_in[3];
    const float* qbv   = (const float*)d_in[4];
    const float* kvw   = (const float*)d_in[5];
    const float* kvbv  = (const float*)d_in[6];
    const float* rpb   = (const float*)d_in[7];
    const float* gamma = (const float*)d_in[8];
    const float* pw    = (const float*)d_in[9];
    const float* pbv   = (const float*)d_in[10];
    ushort* wbf = (ushort*)d_ws;   // qw_bf | kvw_bf | pw_bf

    prep_weights<<<576, 256, 0, stream>>>(qw, kvw, pw, wbf);

    ushort* cmb = wbf + 147456;
    ushort* Qf  = wbf + 1720320;
    ushort* Kf  = wbf + 26886144;
    ushort* Vf  = wbf + 52051968;
    prep_cmb<<<1536, 256, 0, stream>>>(rpb, mask, cmb);
    proj_qkv<<<2048, 256, 0, stream>>>(x1, x2, qbv, kvbv,
                                       wbf, wbf + 36864, Qf, Kf, Vf);
    attn_lam<<<2048, 384, 0, stream>>>(Qf, Kf, Vf, cmb, x1, gamma,
                                       wbf + 110592, pbv, (float*)d_out);
}

// Round 5
// 296.581 us; speedup vs baseline: 1.4284x; 1.1018x over previous
//
#include <hip/hip_runtime.h>

#define DIM 192
#define NTOK 64
#define NHEAD 6
#define HDIM 32
#define SCALE 0.17677669529663687f

typedef __attribute__((ext_vector_type(8))) short bf16x8;
typedef __attribute__((ext_vector_type(4))) float f32x4;

__device__ __forceinline__ ushort f2bf(float f) {
    union { float f; unsigned u; } x; x.f = f;
    unsigned r = x.u + 0x7FFFu + ((x.u >> 16) & 1u);
    return (ushort)(r >> 16);
}
__device__ __forceinline__ float bf2f(ushort h) {
    union { unsigned u; float f; } x; x.u = ((unsigned)h) << 16;
    return x.f;
}

__device__ __forceinline__ f32x4 MF(bf16x8 a, bf16x8 b, f32x4 c) {
    return __builtin_amdgcn_mfma_f32_16x16x32_bf16(a, b, c, 0, 0, 0);
}

// A/B fragment load for 16x16x32 bf16 mfma from a row-major bf16 matrix.
__device__ __forceinline__ bf16x8 frag(const ushort* base, int stride, int r0, int k0) {
    const int l = threadIdx.x & 63;
    return *(const bf16x8*)(base + (r0 + (l & 15)) * stride + (k0 + ((l >> 4) << 3)));
}

__global__ void prep_weights(const float* __restrict__ qw, const float* __restrict__ kvw,
                             const float* __restrict__ pw, ushort* __restrict__ wbf) {
    int i = blockIdx.x * 256 + threadIdx.x;
    if (i < 36864) wbf[i] = f2bf(qw[i]);
    else if (i < 110592) wbf[i] = f2bf(kvw[i - 36864]);
    else if (i < 147456) wbf[i] = f2bf(pw[i - 110592]);
}

// cmb[w][h][m][n] = rpb_bias(h,n,m) + mask[w][n][m]   (bf16)
__global__ void prep_cmb(const float* __restrict__ rpb, const float* __restrict__ mask,
                         ushort* __restrict__ cmb) {
    int t = blockIdx.x * 256 + threadIdx.x;
    int e = t << 2;
    int n0 = e & 63;
    int m  = (e >> 6) & 63;
    int hw = e >> 12;
    int h = hw % 6, w = hw / 6;
#pragma unroll
    for (int j = 0; j < 4; ++j) {
        int n = n0 + j;
        int ridx = ((n >> 3) - (m >> 3) + 7) * 15 + ((n & 7) - (m & 7) + 7);
        float v = rpb[ridx * 6 + h] + mask[(w * 64 + n) * 64 + m];
        cmb[e + j] = f2bf(v);
    }
}

// ---------------- Kernel A: projections (split: even blocks KV, odd blocks Q) ----
__global__ __launch_bounds__(256, 3) void proj_qkv(
    const float* __restrict__ x1, const float* __restrict__ x2,
    const float* __restrict__ qb, const float* __restrict__ kvb,
    const ushort* __restrict__ qwbf, const ushort* __restrict__ kvwbf,
    ushort* __restrict__ Qf, ushort* __restrict__ Kf, ushort* __restrict__ Vf)
{
    __shared__ __align__(16) ushort sXA[64 * 200];
    __shared__ __align__(16) ushort stg[4 * 2560];
    const int tid = threadIdx.x, wave = tid >> 6, lane = tid & 63;
    const int g = lane >> 4, mcol = lane & 15;
    const int b = blockIdx.x >> 1;
    const int kind = blockIdx.x & 1;     // 0: K/V from x2 ; 1: Q from x1
    ushort* st = stg + wave * 2560;

    {
        const float4* src = (const float4*)((kind ? x1 : x2) + (size_t)b * 12288);
        for (int i = tid; i < 3072; i += 256) {
            float4 v = src[i];
            int e = i << 2; int n = e / DIM; int c = e - n * DIM;
            ushort4 w;
            ((ushort*)&w)[0] = f2bf(v.x); ((ushort*)&w)[1] = f2bf(v.y);
            ((ushort*)&w)[2] = f2bf(v.z); ((ushort*)&w)[3] = f2bf(v.w);
            *(ushort4*)(&sXA[n * 200 + c]) = w;
        }
    }
    __syncthreads();

    if (kind == 0) {
        for (int t = wave; t < 12; t += 4) {
            const int isV = (t >= 6) ? 1 : 0;
            const int h = isV ? (t - 6) : t;
            bf16x8 wf[2][6];
#pragma unroll
            for (int c2 = 0; c2 < 2; ++c2) {
                int ctg = (isV ? (12 + 2 * h) : (2 * h)) + c2;
#pragma unroll
                for (int ks = 0; ks < 6; ++ks)
                    wf[c2][ks] = frag(kvwbf, DIM, ctg * 16, ks * 32);
            }
            f32x4 acc[4][2];
#pragma unroll
            for (int rt = 0; rt < 4; ++rt)
#pragma unroll
                for (int c2 = 0; c2 < 2; ++c2) acc[rt][c2] = (f32x4){0.f, 0.f, 0.f, 0.f};
#pragma unroll
            for (int rt = 0; rt < 4; ++rt) {
                bf16x8 af[6];
#pragma unroll
                for (int ks = 0; ks < 6; ++ks) af[ks] = frag(sXA, 200, rt * 16, ks * 32);
#pragma unroll
                for (int c2 = 0; c2 < 2; ++c2)
#pragma unroll
                    for (int ks = 0; ks < 6; ++ks)
                        acc[rt][c2] = MF(af[ks], wf[c2][ks], acc[rt][c2]);
            }
            if (!isV) {
#pragma unroll
                for (int c2 = 0; c2 < 2; ++c2) {
                    float bv = kvb[h * 32 + c2 * 16 + mcol];
#pragma unroll
                    for (int rt = 0; rt < 4; ++rt)
#pragma unroll
                        for (int j = 0; j < 4; ++j)
                            st[(rt * 16 + (g << 2) + j) * 40 + c2 * 16 + mcol] = f2bf(acc[rt][c2][j] + bv);
                }
                asm volatile("s_waitcnt lgkmcnt(0)" ::: "memory");
#pragma unroll
                for (int ct = 0; ct < 4; ++ct) {
                    bf16x8 fr = frag(st, 40, ct * 16, 0);
                    *(bf16x8*)(Kf + ((size_t)(b * 6 + h) * 4 + ct) * 512 + lane * 8) = fr;
                }
                asm volatile("s_waitcnt lgkmcnt(0)" ::: "memory");
            } else {
#pragma unroll
                for (int c2 = 0; c2 < 2; ++c2) {
                    float bv = kvb[192 + h * 32 + c2 * 16 + mcol];
#pragma unroll
                    for (int rt = 0; rt < 4; ++rt) {
                        ushort4 w4;
#pragma unroll
                        for (int j = 0; j < 4; ++j) ((ushort*)&w4)[j] = f2bf(acc[rt][c2][j] + bv);
                        *(ushort4*)(&st[(c2 * 16 + mcol) * 72 + rt * 16 + (g << 2)]) = w4;
                    }
                }
                asm volatile("s_waitcnt lgkmcnt(0)" ::: "memory");
#pragma unroll
                for (int c = 0; c < 2; ++c)
#pragma unroll
                    for (int ctd = 0; ctd < 2; ++ctd) {
                        bf16x8 fr = frag(st, 72, ctd * 16, c * 32);
                        *(bf16x8*)(Vf + (((size_t)(b * 6 + h) * 2 + c) * 2 + ctd) * 512 + lane * 8) = fr;
                    }
                asm volatile("s_waitcnt lgkmcnt(0)" ::: "memory");
            }
        }
    } else {
        for (int t = wave; t < 6; t += 4) {
            const int h = t;
            bf16x8 wf[2][6];
#pragma unroll
            for (int c2 = 0; c2 < 2; ++c2)
#pragma unroll
                for (int ks = 0; ks < 6; ++ks)
                    wf[c2][ks] = frag(qwbf, DIM, (2 * h + c2) * 16, ks * 32);
            f32x4 acc[4][2];
#pragma unroll
            for (int rt = 0; rt < 4; ++rt)
#pragma unroll
                for (int c2 = 0; c2 < 2; ++c2) acc[rt][c2] = (f32x4){0.f, 0.f, 0.f, 0.f};
#pragma unroll
            for (int rt = 0; rt < 4; ++rt) {
                bf16x8 af[6];
#pragma unroll
                for (int ks = 0; ks < 6; ++ks) af[ks] = frag(sXA, 200, rt * 16, ks * 32);
#pragma unroll
                for (int c2 = 0; c2 < 2; ++c2)
#pragma unroll
                    for (int ks = 0; ks < 6; ++ks)
                        acc[rt][c2] = MF(af[ks], wf[c2][ks], acc[rt][c2]);
            }
#pragma unroll
            for (int c2 = 0; c2 < 2; ++c2) {
                float bv = qb[h * 32 + c2 * 16 + mcol];
#pragma unroll
                for (int rt = 0; rt < 4; ++rt)
#pragma unroll
                    for (int j = 0; j < 4; ++j)
                        st[(rt * 16 + (g << 2) + j) * 40 + c2 * 16 + mcol] =
                            f2bf((acc[rt][c2][j] + bv) * SCALE);
            }
            asm volatile("s_waitcnt lgkmcnt(0)" ::: "memory");
#pragma unroll
            for (int rt = 0; rt < 4; ++rt) {
                bf16x8 fr = frag(st, 40, rt * 16, 0);
                *(bf16x8*)(Qf + ((size_t)(b * 6 + h) * 4 + rt) * 512 + lane * 8) = fr;
            }
            asm volatile("s_waitcnt lgkmcnt(0)" ::: "memory");
        }
    }
}

// ---------------- Kernel B1: attention, 1 wave per (window,head), no barriers ----
// Y [d][n] (32x64 bf16) overwrites the dead Kf slot of the same (window,head).
__global__ __launch_bounds__(256, 4) void attn_heads(
    const ushort* __restrict__ Qf, ushort* KfY,
    const ushort* __restrict__ Vf, const ushort* __restrict__ cmb)
{
    __shared__ __align__(16) ushort sP[4 * 1280];   // per-wave P slice [16][72]
    const int tid = threadIdx.x, wave = tid >> 6, lane = tid & 63;
    const int g = lane >> 4, mcol = lane & 15;
    const int gid = blockIdx.x * 4 + wave;          // 0..12287
    const int w = gid / 6, h = gid - 6 * (gid / 6);
    const f32x4 zero4 = {0.f, 0.f, 0.f, 0.f};

    const ushort* qp = Qf  + (size_t)gid * 2048;
    ushort*       kp = KfY + (size_t)gid * 2048;
    const ushort* vp = Vf  + (size_t)gid * 2048;
    const ushort* cp = cmb + (size_t)((w & 63) * 6 + h) * 4096;
    ushort* slot = sP + wave * 1280;

    bf16x8 kb[4], vb[4];
#pragma unroll
    for (int ct = 0; ct < 4; ++ct) kb[ct] = *(const bf16x8*)(kp + ct * 512 + lane * 8);
#pragma unroll
    for (int c = 0; c < 4; ++c) vb[c] = *(const bf16x8*)(vp + c * 512 + lane * 8);

    ushort4 y4[4][2];
#pragma unroll
    for (int rt = 0; rt < 4; ++rt) {
        bf16x8 qa = *(const bf16x8*)(qp + rt * 512 + lane * 8);
        f32x4 acc[4];
#pragma unroll
        for (int ct = 0; ct < 4; ++ct) acc[ct] = MF(qa, kb[ct], zero4);
#pragma unroll
        for (int ct = 0; ct < 4; ++ct) {
            ushort4 b4 = *(const ushort4*)(cp + (ct * 16 + mcol) * 64 + rt * 16 + (g << 2));
#pragma unroll
            for (int j = 0; j < 4; ++j) acc[ct][j] += bf2f(((ushort*)&b4)[j]);
        }
        float sm[4];
#pragma unroll
        for (int j = 0; j < 4; ++j) {
            float v = fmaxf(fmaxf(acc[0][j], acc[1][j]), fmaxf(acc[2][j], acc[3][j]));
            v = fmaxf(v, __shfl_xor(v, 1, 64));
            v = fmaxf(v, __shfl_xor(v, 2, 64));
            v = fmaxf(v, __shfl_xor(v, 4, 64));
            v = fmaxf(v, __shfl_xor(v, 8, 64));
            float s = 0.f;
#pragma unroll
            for (int ct = 0; ct < 4; ++ct) {
                float p = __expf(acc[ct][j] - v);
                acc[ct][j] = p; s += p;
            }
            s += __shfl_xor(s, 1, 64);
            s += __shfl_xor(s, 2, 64);
            s += __shfl_xor(s, 4, 64);
            s += __shfl_xor(s, 8, 64);
            sm[j] = 1.0f / s;
        }
#pragma unroll
        for (int ct = 0; ct < 4; ++ct)
#pragma unroll
            for (int j = 0; j < 4; ++j)
                slot[((g << 2) + j) * 72 + ct * 16 + mcol] = f2bf(acc[ct][j] * sm[j]);
        asm volatile("s_waitcnt lgkmcnt(0)" ::: "memory");
        f32x4 ay0 = zero4, ay1 = zero4;
#pragma unroll
        for (int c = 0; c < 2; ++c) {
            bf16x8 pa = frag(slot, 72, 0, c * 32);
            ay0 = MF(pa, vb[c * 2 + 0], ay0);
            ay1 = MF(pa, vb[c * 2 + 1], ay1);
        }
        asm volatile("s_waitcnt lgkmcnt(0)" ::: "memory");
#pragma unroll
        for (int j = 0; j < 4; ++j) {
            ((ushort*)&y4[rt][0])[j] = f2bf(ay0[j]);
            ((ushort*)&y4[rt][1])[j] = f2bf(ay1[j]);
        }
    }
    // write Y [d][n] over dead Kf slot (all kp reads completed above)
#pragma unroll
    for (int rt = 0; rt < 4; ++rt)
#pragma unroll
        for (int ctd = 0; ctd < 2; ++ctd)
            *(ushort4*)(kp + (ctd * 16 + mcol) * 64 + rt * 16 + (g << 2)) = y4[rt][ctd];
}

// ---------------- Kernel B2: LAM + residual + output projection ----------------
__global__ __launch_bounds__(256, 4) void lam_proj(
    const ushort* __restrict__ Yd, const ushort* __restrict__ Qf,
    const float* __restrict__ x1, const float* __restrict__ gammap,
    const ushort* __restrict__ pwbf, const float* __restrict__ pb,
    float* __restrict__ out)
{
    __shared__ __align__(16) ushort sYF[13824];   // Y [6][32][72] ; later finalX [64][200]
    __shared__ __align__(16) float  sE[32 * 33];
    __shared__ __align__(16) ushort sAtt[32 * 40];

    const int tid = threadIdx.x, wave = tid >> 6, lane = tid & 63;
    const int g = lane >> 4, mcol = lane & 15;
    const int b = blockIdx.x;
    const float gamma = gammap[0];
    const f32x4 zero4 = {0.f, 0.f, 0.f, 0.f};

    // coop load Yd (6 heads x [32][64] ushort) -> LDS [6][32][72]
    // 6*32*64 = 12288 ushorts = 3072 ushort4; 12 per thread
    {
        const ushort* src = Yd + (size_t)b * 12288;
        for (int i = tid; i < 3072; i += 256) {
            int hd = i >> 9;            // 512 ushort4 per head
            int rem = i & 511;
            int row = rem >> 4, k4 = rem & 15;
            ushort4 v = *(const ushort4*)(src + hd * 2048 + row * 64 + k4 * 4);
            *(ushort4*)(&sYF[hd * 2304 + row * 72 + k4 * 4]) = v;
        }
    }
    __syncthreads();

    // energy = flat @ flat^T [32x32], K=384; 4 waves, one 16x16 tile each
    {
        int rt = wave >> 1, ct = wave & 1;
        f32x4 a0 = zero4, a1 = zero4;
#pragma unroll
        for (int hd = 0; hd < 6; hd += 2) {
            const ushort* Y0 = sYF + hd * 2304;
            const ushort* Y1 = sYF + (hd + 1) * 2304;
#pragma unroll
            for (int kk = 0; kk < 2; ++kk) {
                a0 = MF(frag(Y0, 72, rt * 16, kk * 32), frag(Y0, 72, ct * 16, kk * 32), a0);
                a1 = MF(frag(Y1, 72, rt * 16, kk * 32), frag(Y1, 72, ct * 16, kk * 32), a1);
            }
        }
        f32x4 acc = a0 + a1;
#pragma unroll
        for (int j = 0; j < 4; ++j)
            sE[(rt * 16 + (g << 2) + j) * 33 + ct * 16 + mcol] = acc[j];
    }
    __syncthreads();

    // softmax rows of energy -> att bf16 (32 rows x 8 lanes)
    {
        int r = tid >> 3, l8 = tid & 7;
        float e[4];
        float mx = -1e30f;
#pragma unroll
        for (int k = 0; k < 4; ++k) { e[k] = sE[r * 33 + l8 + k * 8]; mx = fmaxf(mx, e[k]); }
        mx = fmaxf(mx, __shfl_xor(mx, 1, 64));
        mx = fmaxf(mx, __shfl_xor(mx, 2, 64));
        mx = fmaxf(mx, __shfl_xor(mx, 4, 64));
        float s = 0.f;
#pragma unroll
        for (int k = 0; k < 4; ++k) { e[k] = __expf(e[k] - mx); s += e[k]; }
        s += __shfl_xor(s, 1, 64);
        s += __shfl_xor(s, 2, 64);
        s += __shfl_xor(s, 4, 64);
        float rs = 1.0f / s;
#pragma unroll
        for (int k = 0; k < 4; ++k) sAtt[r * 40 + l8 + k * 8] = f2bf(e[k] * rs);
    }
    __syncthreads();

    // outm = att @ flat ; finalX = gamma*outm + flat + (q̂ + x1)
    ushort4 w4st[12];
#pragma unroll
    for (int i = 0; i < 12; ++i) {
        int t = wave + i * 4;
        int rtL = t & 1, ct = t >> 1;
        int col = ct * 16 + mcol;
        int hh = col >> 6, nn = col & 63;
        const ushort* Yh = sYF + hh * 2304;
        bf16x8 aa = frag(sAtt, 40, rtL * 16, 0);
        bf16x8 bb;
#pragma unroll
        for (int jj = 0; jj < 8; ++jj) bb[jj] = (short)Yh[((g << 3) + jj) * 72 + nn];
        f32x4 acc = MF(aa, bb, zero4);
        int d0 = rtL * 16 + (g << 2);
        ushort4 qv4 = *(const ushort4*)(Qf + (size_t)(b * 6 + hh) * 2048 +
                                        (nn >> 4) * 512 + ((nn & 15) + ((d0 >> 3) << 4)) * 8 + (d0 & 7));
        float4 xv4 = *(const float4*)(x1 + (size_t)b * 12288 + nn * 192 + hh * 32 + d0);
        ushort4 w4;
#pragma unroll
        for (int j = 0; j < 4; ++j) {
            float flatv = bf2f(Yh[(d0 + j) * 72 + nn]);
            float val = gamma * acc[j] + flatv + bf2f(((ushort*)&qv4)[j]) + ((const float*)&xv4)[j];
            ((ushort*)&w4)[j] = f2bf(val);
        }
        w4st[i] = w4;
    }
    __syncthreads();
#pragma unroll
    for (int i = 0; i < 12; ++i) {
        int t = wave + i * 4;
        int rtL = t & 1, ct = t >> 1;
        int col = ct * 16 + mcol;
        int hh = col >> 6, nn = col & 63;
        int d0 = rtL * 16 + (g << 2);
        *(ushort4*)(&sYF[nn * 200 + hh * 32 + d0]) = w4st[i];
    }
    __syncthreads();

    // out = finalX @ pw^T + pb ; wave = row-band, af loaded once
    {
        float* outp = out + (size_t)b * 12288;
        const int rt = wave;
        bf16x8 af[6];
#pragma unroll
        for (int ks = 0; ks < 6; ++ks) af[ks] = frag(sYF, 200, rt * 16, ks * 32);
        for (int ct = 0; ct < 12; ++ct) {
            f32x4 acc = zero4;
#pragma unroll
            for (int ks = 0; ks < 6; ++ks)
                acc = MF(af[ks], frag(pwbf, DIM, ct * 16, ks * 32), acc);
            int co = ct * 16 + mcol;
            float pbv = pb[co];
#pragma unroll
            for (int j = 0; j < 4; ++j)
                outp[(rt * 16 + (g << 2) + j) * DIM + co] = acc[j] + pbv;
        }
    }
}

extern "C" void kernel_launch(void* const* d_in, const int* in_sizes, int n_in,
                              void* d_out, int out_size, void* d_ws, size_t ws_size,
                              hipStream_t stream) {
    const float* x1    = (const float*)d_in[0];
    const float* x2    = (const float*)d_in[1];
    const float* mask  = (const float*)d_in[2];
    const float* qw    = (const float*)d_in[3];
    const float* qbv   = (const float*)d_in[4];
    const float* kvw   = (const float*)d_in[5];
    const float* kvbv  = (const float*)d_in[6];
    const float* rpb   = (const float*)d_in[7];
    const float* gamma = (const float*)d_in[8];
    const float* pw    = (const float*)d_in[9];
    const float* pbv   = (const float*)d_in[10];
    ushort* wbf = (ushort*)d_ws;   // qw_bf | kvw_bf | pw_bf

    prep_weights<<<576, 256, 0, stream>>>(qw, kvw, pw, wbf);

    ushort* cmb = wbf + 147456;
    ushort* Qf  = wbf + 1720320;
    ushort* Kf  = wbf + 26886144;    // becomes Y [d][n] after attn_heads
    ushort* Vf  = wbf + 52051968;
    prep_cmb<<<1536, 256, 0, stream>>>(rpb, mask, cmb);
    proj_qkv<<<4096, 256, 0, stream>>>(x1, x2, qbv, kvbv,
                                       wbf, wbf + 36864, Qf, Kf, Vf);
    attn_heads<<<3072, 256, 0, stream>>>(Qf, Kf, Vf, cmb);
    lam_proj<<<2048, 256, 0, stream>>>(Kf, Qf, x1, gamma,
                                       wbf + 110592, pbv, (float*)d_out);
}